// Round 10
// baseline (183.112 us; speedup 1.0000x reference)
//
#include <hip/hip_runtime.h>

#define TPB 256
#define NWAVE (TPB / 64)
#define GRID_MAIN 2048

typedef int vi2 __attribute__((ext_vector_type(2)));
typedef int vi4 __attribute__((ext_vector_type(4)));

// Unified chunk space (64-term chunks), cumulative ends: bond|angle|torsion|inversion|LJ.
struct SegInfo {
    int cb, ca, ct, ci, cl;
    int NB, NA, NT, NI, NC;
    int N;
};

__device__ __forceinline__ float clamp1(float x) {
    return fminf(fmaxf(x, -0.999999f), 0.999999f);
}

__device__ __forceinline__ float ntf(const float* p) { return __builtin_nontemporal_load(p); }
__device__ __forceinline__ int   nti(const int* p)   { return __builtin_nontemporal_load(p); }

// Half-table layout: cwH = float4[atom][4] (batches h*4..h*4+3), 64 B/atom, 64B-aligned.
// 3.2 MB per half at N=50k -> one XCD's 4 MiB L2 holds its half entirely.
// A 4-lane group's gather = 4 consecutive dwordx4 = ONE 64B line.
template <bool USE_WS>
__device__ __forceinline__ float4 loadC(const float4* __restrict__ cwH,
                                        const float* __restrict__ coords,
                                        int N, int atom, int batch, int b4) {
    if (USE_WS) {
        return cwH[((size_t)atom << 2) + b4];
    } else {
        const float* sp = coords + ((size_t)batch * N + atom) * 3;
        return make_float4(sp[0], sp[1], sp[2], 0.f);
    }
}

// coords (B,N,3) -> cwA (batches 0-3), cwB (batches 4-7); also zeroes d_out.
__global__ void __launch_bounds__(TPB) transpose_coords(const float* __restrict__ coords,
                                                        float4* __restrict__ cwA,
                                                        float4* __restrict__ cwB,
                                                        float* __restrict__ out, int N) {
    const int a = blockIdx.x * TPB + threadIdx.x;
    if (blockIdx.x == 0 && threadIdx.x < 8) out[threadIdx.x] = 0.f;
    if (a >= N) return;
#pragma unroll
    for (int b = 0; b < 8; b++) {
        const float* sp = coords + ((size_t)b * N + a) * 3;
        float4 v = make_float4(ntf(sp), ntf(sp + 1), ntf(sp + 2), 0.f);
        if (b < 4) cwA[((size_t)a << 2) + b] = v;
        else       cwB[((size_t)a << 2) + (b - 4)] = v;
    }
}

template <bool USE_WS>
__global__ void __launch_bounds__(TPB, 8) uff_kernel(
    const float* __restrict__ coords,
    const float4* __restrict__ cwA, const float4* __restrict__ cwB,
    const int* __restrict__ bidx, const float* __restrict__ br0, const float* __restrict__ bk,
    const int* __restrict__ aidx, const float* __restrict__ ak,
    const float* __restrict__ ac0, const float* __restrict__ ac1, const float* __restrict__ ac2,
    const int* __restrict__ tidx, const float* __restrict__ tk,
    const int* __restrict__ tord, const float* __restrict__ tcos,
    const int* __restrict__ iidx, const float* __restrict__ ik,
    const float* __restrict__ ic0, const float* __restrict__ ic1, const float* __restrict__ ic2,
    const int* __restrict__ nidx, const float* __restrict__ vmin,
    const float* __restrict__ vdep, const float* __restrict__ vthr,
    float* __restrict__ out, SegInfo s)
{
    // Per-wave staging slice (8 KB/block). Barrier-free: only the owning wave
    // touches its slice (same-wave ds ordering via lgkmcnt).
    __shared__ int4   sI[NWAVE][64];
    __shared__ float4 sP[NWAVE][64];

    const int tid = threadIdx.x;
    const int lane = tid & 63;
    const int w = tid >> 6;
    const int b4 = lane & 3;      // batch within half
    const int gwi = lane >> 2;    // group within wave, 0..15 (4 lanes/group)
    const int N = s.N;

    // XCD steering: blocks with (blockIdx%8)<4 handle batches 0-3 (cwA); rest cwB.
    // Every chunk is processed once per half, by different XCD-pinned blocks.
    const int half = ((blockIdx.x & 7) < 4) ? 0 : 1;
    const int batch = half * 4 + b4;
    const float4* cwH = half ? cwB : cwA;

    float acc = 0.f;

    int4*   mI = sI[w];
    float4* mP = sP[w];

    // Within-half wave index / stride ((blockIdx&3) == within-XCD-quad index for both halves).
    const int hb = (blockIdx.x >> 3) * 4 + (blockIdx.x & 3);
    const int stride = (gridDim.x >> 1) * NWAVE;
    int c = hb * NWAVE + w;

    for (; c < s.cl; c += stride) {
        // ---------------- stage this wave's 64 terms ----------------
        int kind, base;
        if (c < s.cb)      { kind = 0; base = c * 64; }
        else if (c < s.ca) { kind = 1; base = (c - s.cb) * 64; }
        else if (c < s.ct) { kind = 2; base = (c - s.ca) * 64; }
        else if (c < s.ci) { kind = 3; base = (c - s.ct) * 64; }
        else               { kind = 4; base = (c - s.ci) * 64; }

        if (kind == 0) {
            const int u = min(base + lane, s.NB - 1);
            const vi2 ij = __builtin_nontemporal_load((const vi2*)bidx + u);
            mI[lane] = make_int4(ij.x, ij.y, 0, 0);
            mP[lane] = make_float4(ntf(br0 + u), ntf(bk + u), 0.f, 0.f);
        } else if (kind == 1) {
            const int u = min(base + lane, s.NA - 1);
            mI[lane] = make_int4(aidx[3 * u], aidx[3 * u + 1], aidx[3 * u + 2], 0);
            mP[lane] = make_float4(ntf(ak + u), ntf(ac0 + u), ntf(ac1 + u), ntf(ac2 + u));
        } else if (kind == 2) {
            const int u = min(base + lane, s.NT - 1);
            const vi4 q = __builtin_nontemporal_load((const vi4*)tidx + u);
            mI[lane] = make_int4(q.x, q.y, q.z, q.w);
            mP[lane] = make_float4(ntf(tk + u), ntf(tcos + u),
                                   __int_as_float(nti(tord + u)), 0.f);
        } else if (kind == 3) {
            const int u = min(base + lane, s.NI - 1);
            const vi4 q = __builtin_nontemporal_load((const vi4*)iidx + u);  // i, central, k, l
            mI[lane] = make_int4(q.x, q.y, q.z, q.w);
            mP[lane] = make_float4(ntf(ik + u), ntf(ic0 + u), ntf(ic1 + u), ntf(ic2 + u));
        } else {
            const int u = min(base + lane, s.NC - 1);
            const vi2 ij = __builtin_nontemporal_load((const vi2*)nidx + u);
            const float R = ntf(vmin + u);
            mI[lane] = make_int4(ij.x, ij.y, 0, 0);
            mP[lane] = make_float4(R * R, ntf(vdep + u), ntf(vthr + u), 0.f);
        }
        // (compiler inserts s_waitcnt lgkmcnt before the reads below — same-wave LDS)

        // ------- process: 4 lanes per term (one 64B line per gather), 4 terms/group -------
        if (kind == 4) {
            // vdW LJ: 2 terms per group per iteration (4 gathers in flight)
#pragma unroll
            for (int j = 0; j < 2; j++) {
                const int s0 = j * 16 + gwi, s1 = s0 + 32;
                const int4 q0 = mI[s0]; const float4 p0 = mP[s0];
                const int4 q1 = mI[s1]; const float4 p1 = mP[s1];
                float4 a0 = loadC<USE_WS>(cwH, coords, N, q0.x, batch, b4);
                float4 b0 = loadC<USE_WS>(cwH, coords, N, q0.y, batch, b4);
                float4 a1 = loadC<USE_WS>(cwH, coords, N, q1.x, batch, b4);
                float4 b1 = loadC<USE_WS>(cwH, coords, N, q1.y, batch, b4);
                {
                    float dx = a0.x - b0.x, dy = a0.y - b0.y, dz = a0.z - b0.z;
                    float d2 = dx * dx + dy * dy + dz * dz;
                    float x2 = p0.x / fmaxf(d2, 1e-12f);
                    float x6 = x2 * x2 * x2;
                    float e = p0.y * (x6 * x6 - 2.f * x6);
                    if (base + s0 < s.NC && d2 <= p0.z) acc += e;
                }
                {
                    float dx = a1.x - b1.x, dy = a1.y - b1.y, dz = a1.z - b1.z;
                    float d2 = dx * dx + dy * dy + dz * dz;
                    float x2 = p1.x / fmaxf(d2, 1e-12f);
                    float x6 = x2 * x2 * x2;
                    float e = p1.y * (x6 * x6 - 2.f * x6);
                    if (base + s1 < s.NC && d2 <= p1.z) acc += e;
                }
            }
        } else if (kind == 0) {
            // bond stretch: 2 terms per iteration
#pragma unroll
            for (int j = 0; j < 2; j++) {
                const int s0 = j * 16 + gwi, s1 = s0 + 32;
                const int4 q0 = mI[s0]; const float4 p0 = mP[s0];
                const int4 q1 = mI[s1]; const float4 p1 = mP[s1];
                float4 a0 = loadC<USE_WS>(cwH, coords, N, q0.x, batch, b4);
                float4 b0 = loadC<USE_WS>(cwH, coords, N, q0.y, batch, b4);
                float4 a1 = loadC<USE_WS>(cwH, coords, N, q1.x, batch, b4);
                float4 b1 = loadC<USE_WS>(cwH, coords, N, q1.y, batch, b4);
                {
                    float dx = a0.x - b0.x, dy = a0.y - b0.y, dz = a0.z - b0.z;
                    float dd = sqrtf(dx * dx + dy * dy + dz * dz) - p0.x;
                    if (base + s0 < s.NB) acc += 0.5f * p0.y * dd * dd;
                }
                {
                    float dx = a1.x - b1.x, dy = a1.y - b1.y, dz = a1.z - b1.z;
                    float dd = sqrtf(dx * dx + dy * dy + dz * dz) - p1.x;
                    if (base + s1 < s.NB) acc += 0.5f * p1.y * dd * dd;
                }
            }
        } else if (kind == 1) {
            // angle bend: 1 term per iteration (3 gathers in flight)
#pragma unroll
            for (int j = 0; j < 4; j++) {
                const int slot = j * 16 + gwi;
                const int4 q = mI[slot]; const float4 p = mP[slot];
                float4 P = loadC<USE_WS>(cwH, coords, N, q.x, batch, b4);
                float4 Q = loadC<USE_WS>(cwH, coords, N, q.y, batch, b4);
                float4 R = loadC<USE_WS>(cwH, coords, N, q.z, batch, b4);
                float ax = P.x - Q.x, ay = P.y - Q.y, az = P.z - Q.z;
                float bx = R.x - Q.x, by = R.y - Q.y, bz = R.z - Q.z;
                float dot = ax * bx + ay * by + az * bz;
                float nn = (ax * ax + ay * ay + az * az) * (bx * bx + by * by + bz * bz);
                float ct = clamp1(dot * rsqrtf(fmaxf(nn, 1e-24f)));
                float cs = ct * ct;
                float sb = fmaxf(1.f - cs, 1e-12f);
                if (base + slot < s.NA) acc += p.x * (p.y + p.z * ct + p.w * (cs - sb));
            }
        } else if (kind == 2) {
            // torsion: 1 term per iteration (4 gathers in flight)
#pragma unroll
            for (int j = 0; j < 4; j++) {
                const int slot = j * 16 + gwi;
                const int4 q = mI[slot]; const float4 p = mP[slot];
                const int ord = __float_as_int(p.z);
                float4 P1 = loadC<USE_WS>(cwH, coords, N, q.x, batch, b4);
                float4 P2 = loadC<USE_WS>(cwH, coords, N, q.y, batch, b4);
                float4 P3 = loadC<USE_WS>(cwH, coords, N, q.z, batch, b4);
                float4 P4 = loadC<USE_WS>(cwH, coords, N, q.w, batch, b4);
                float b1x = P2.x - P1.x, b1y = P2.y - P1.y, b1z = P2.z - P1.z;
                float b2x = P3.x - P2.x, b2y = P3.y - P2.y, b2z = P3.z - P2.z;
                float b3x = P4.x - P3.x, b3y = P4.y - P3.y, b3z = P4.z - P3.z;
                float n1x = b1y * b2z - b1z * b2y;
                float n1y = b1z * b2x - b1x * b2z;
                float n1z = b1x * b2y - b1y * b2x;
                float n2x = b2y * b3z - b2z * b3y;
                float n2y = b2z * b3x - b2x * b3z;
                float n2z = b2x * b3y - b2y * b3x;
                float dot = n1x * n2x + n1y * n2y + n1z * n2z;
                float nn = (n1x * n1x + n1y * n1y + n1z * n1z) *
                           (n2x * n2x + n2y * n2y + n2z * n2z);
                float x = clamp1(dot * rsqrtf(fmaxf(nn, 1e-24f)));
                // cos(n*acos(x)) = T_n(x), n in [1,6]
                float Tp = 1.f, Tc = x, res = x;
#pragma unroll
                for (int kk = 2; kk <= 6; kk++) {
                    float Tn = 2.f * x * Tc - Tp;
                    Tp = Tc; Tc = Tn;
                    if (ord == kk) res = Tn;
                }
                if (base + slot < s.NT) acc += 0.5f * p.x * (1.f - p.y * res);
            }
        } else {
            // inversion (Wilson): 1 term per iteration
#pragma unroll
            for (int j = 0; j < 4; j++) {
                const int slot = j * 16 + gwi;
                const int4 q = mI[slot]; const float4 p = mP[slot];
                float4 CA = loadC<USE_WS>(cwH, coords, N, q.y, batch, b4);
                float4 PI = loadC<USE_WS>(cwH, coords, N, q.x, batch, b4);
                float4 PK = loadC<USE_WS>(cwH, coords, N, q.z, batch, b4);
                float4 PL = loadC<USE_WS>(cwH, coords, N, q.w, batch, b4);
                float jix = PI.x - CA.x, jiy = PI.y - CA.y, jiz = PI.z - CA.z;
                float jkx = PK.x - CA.x, jky = PK.y - CA.y, jkz = PK.z - CA.z;
                float lx  = PL.x - CA.x, ly  = PL.y - CA.y, lz  = PL.z - CA.z;
                float nx = jiy * jkz - jiz * jky;
                float ny = jiz * jkx - jix * jkz;
                float nz = jix * jky - jiy * jkx;
                float dot = nx * lx + ny * ly + nz * lz;
                float nn = (nx * nx + ny * ny + nz * nz) * (lx * lx + ly * ly + lz * lz);
                float cosY = clamp1(dot * rsqrtf(fmaxf(nn, 1e-24f)));
                float sinY = sqrtf(fmaxf(1.f - cosY * cosY, 0.f));
                if (base + slot < s.NI)
                    acc += p.x * (p.y + p.z * sinY + p.w * (2.f * sinY * sinY - 1.f));
            }
        }
    }

    // -------- reduction: lanes with same (lane&3) hold the same batch (this half) --------
    float v = acc;
    v += __shfl_down(v, 4, 64);
    v += __shfl_down(v, 8, 64);
    v += __shfl_down(v, 16, 64);
    v += __shfl_down(v, 32, 64);
    // lanes 0..3 of each wave hold batch (half*4 + 0..3) sums

    __shared__ float red[NWAVE][4];
    if (lane < 4) red[w][lane] = v;
    __syncthreads();
    if (tid < 4) {
        float ssum = 0.f;
#pragma unroll
        for (int i = 0; i < NWAVE; i++) ssum += red[i][tid];
        atomicAdd(&out[half * 4 + tid], ssum);
    }
}

static inline int cdiv(int a, int b) { return (a + b - 1) / b; }

extern "C" void kernel_launch(void* const* d_in, const int* in_sizes, int n_in,
                              void* d_out, int out_size, void* d_ws, size_t ws_size,
                              hipStream_t stream) {
    const int B = out_size;  // expected 8 (kernel hard-codes 8 batches)
    const int NB = in_sizes[2], NA = in_sizes[5], NT = in_sizes[10],
              NI = in_sizes[14], NC = in_sizes[19];
    const int N = in_sizes[0] / (3 * B);

    const float* coords = (const float*)d_in[0];
    const int*   bidx = (const int*)d_in[1];
    const float* br0  = (const float*)d_in[2];
    const float* bk   = (const float*)d_in[3];
    const int*   aidx = (const int*)d_in[4];
    const float* ak   = (const float*)d_in[5];
    const float* ac0  = (const float*)d_in[6];
    const float* ac1  = (const float*)d_in[7];
    const float* ac2  = (const float*)d_in[8];
    const int*   tidx = (const int*)d_in[9];
    const float* tk   = (const float*)d_in[10];
    const int*   tord = (const int*)d_in[11];
    const float* tcos = (const float*)d_in[12];
    const int*   iidx = (const int*)d_in[13];
    const float* ik   = (const float*)d_in[14];
    const float* ic0  = (const float*)d_in[15];
    const float* ic1  = (const float*)d_in[16];
    const float* ic2  = (const float*)d_in[17];
    const int*   nidx = (const int*)d_in[18];
    const float* vmin = (const float*)d_in[19];
    const float* vdep = (const float*)d_in[20];
    const float* vthr = (const float*)d_in[21];

    const size_t half_bytes = (size_t)N * 4 * sizeof(float4);
    const bool use_ws = ws_size >= 2 * half_bytes;
    float4* cwA = (float4*)d_ws;
    float4* cwB = (float4*)((char*)d_ws + half_bytes);

    if (use_ws) {
        transpose_coords<<<cdiv(N, TPB), TPB, 0, stream>>>(coords, cwA, cwB, (float*)d_out, N);
    } else {
        hipMemsetAsync(d_out, 0, (size_t)out_size * sizeof(float), stream);
    }

    SegInfo s;
    s.NB = NB; s.NA = NA; s.NT = NT; s.NI = NI; s.NC = NC; s.N = N;
    s.cb = cdiv(NB, 64);
    s.ca = s.cb + cdiv(NA, 64);
    s.ct = s.ca + cdiv(NT, 64);
    s.ci = s.ct + cdiv(NI, 64);
    s.cl = s.ci + cdiv(NC, 64);

    if (use_ws) {
        uff_kernel<true><<<GRID_MAIN, TPB, 0, stream>>>(
            coords, cwA, cwB, bidx, br0, bk, aidx, ak, ac0, ac1, ac2,
            tidx, tk, tord, tcos, iidx, ik, ic0, ic1, ic2,
            nidx, vmin, vdep, vthr, (float*)d_out, s);
    } else {
        uff_kernel<false><<<GRID_MAIN, TPB, 0, stream>>>(
            coords, cwA, cwB, bidx, br0, bk, aidx, ak, ac0, ac1, ac2,
            tidx, tk, tord, tcos, iidx, ik, ic0, ic1, ic2,
            nidx, vmin, vdep, vthr, (float*)d_out, s);
    }
}

// Round 11
// 165.055 us; speedup vs baseline: 1.1094x; 1.1094x over previous
//
#include <hip/hip_runtime.h>

#define TPB 256
#define NWAVE (TPB / 64)
#define GRID_MAIN 2048

typedef int vi2 __attribute__((ext_vector_type(2)));
typedef int vi4 __attribute__((ext_vector_type(4)));

// Unified chunk space (64-term chunks), cumulative ends: bond|angle|torsion|inversion|LJ.
struct SegInfo {
    int cb, ca, ct, ci, cl;
    int NB, NA, NT, NI, NC;
    int N;
};

__device__ __forceinline__ float clamp1(float x) {
    return fminf(fmaxf(x, -0.999999f), 0.999999f);
}

__device__ __forceinline__ float ntf(const float* p) { return __builtin_nontemporal_load(p); }
__device__ __forceinline__ int   nti(const int* p)   { return __builtin_nontemporal_load(p); }

// cw layout: float4[atom][8] — atom's 8 batch replicas contiguous (128 B aligned).
// The 8 lanes of a term-group each load one dwordx4 -> one 128B region per gather.
template <bool USE_WS>
__device__ __forceinline__ float4 loadC(const float4* __restrict__ cw,
                                        const float* __restrict__ coords,
                                        int N, int atom, int b) {
    if (USE_WS) {
        return cw[((size_t)atom << 3) + b];
    } else {
        const float* sp = coords + ((size_t)b * N + atom) * 3;
        return make_float4(sp[0], sp[1], sp[2], 0.f);
    }
}

// coords (B,N,3) -> cw float4[atom][8]; also zeroes d_out.
__global__ void __launch_bounds__(TPB) transpose_coords(const float* __restrict__ coords,
                                                        float4* __restrict__ cw,
                                                        float* __restrict__ out, int N) {
    const int a = blockIdx.x * TPB + threadIdx.x;
    if (blockIdx.x == 0 && threadIdx.x < 8) out[threadIdx.x] = 0.f;
    if (a >= N) return;
#pragma unroll
    for (int b = 0; b < 8; b++) {
        const float* sp = coords + ((size_t)b * N + a) * 3;
        cw[((size_t)a << 3) + b] = make_float4(ntf(sp), ntf(sp + 1), ntf(sp + 2), 0.f);
    }
}

// Load chunk c's term-(lane) indices+params into registers (one term per lane).
__device__ __forceinline__ void stage(
    int c, const SegInfo& s, int lane,
    const int* __restrict__ bidx, const float* __restrict__ br0, const float* __restrict__ bk,
    const int* __restrict__ aidx, const float* __restrict__ ak,
    const float* __restrict__ ac0, const float* __restrict__ ac1, const float* __restrict__ ac2,
    const int* __restrict__ tidx, const float* __restrict__ tk,
    const int* __restrict__ tord, const float* __restrict__ tcos,
    const int* __restrict__ iidx, const float* __restrict__ ik,
    const float* __restrict__ ic0, const float* __restrict__ ic1, const float* __restrict__ ic2,
    const int* __restrict__ nidx, const float* __restrict__ vmin,
    const float* __restrict__ vdep, const float* __restrict__ vthr,
    int4& ri, float4& rp)
{
    if (c < s.cb) {
        const int u = min(c * 64 + lane, s.NB - 1);
        const vi2 ij = __builtin_nontemporal_load((const vi2*)bidx + u);
        ri = make_int4(ij.x, ij.y, 0, 0);
        rp = make_float4(ntf(br0 + u), ntf(bk + u), 0.f, 0.f);
    } else if (c < s.ca) {
        const int u = min((c - s.cb) * 64 + lane, s.NA - 1);
        ri = make_int4(aidx[3 * u], aidx[3 * u + 1], aidx[3 * u + 2], 0);
        rp = make_float4(ntf(ak + u), ntf(ac0 + u), ntf(ac1 + u), ntf(ac2 + u));
    } else if (c < s.ct) {
        const int u = min((c - s.ca) * 64 + lane, s.NT - 1);
        const vi4 q = __builtin_nontemporal_load((const vi4*)tidx + u);
        ri = make_int4(q.x, q.y, q.z, q.w);
        rp = make_float4(ntf(tk + u), ntf(tcos + u), __int_as_float(nti(tord + u)), 0.f);
    } else if (c < s.ci) {
        const int u = min((c - s.ct) * 64 + lane, s.NI - 1);
        const vi4 q = __builtin_nontemporal_load((const vi4*)iidx + u);  // i, central, k, l
        ri = make_int4(q.x, q.y, q.z, q.w);
        rp = make_float4(ntf(ik + u), ntf(ic0 + u), ntf(ic1 + u), ntf(ic2 + u));
    } else {
        const int u = min((c - s.ci) * 64 + lane, s.NC - 1);
        const vi2 ij = __builtin_nontemporal_load((const vi2*)nidx + u);
        const float R = ntf(vmin + u);
        ri = make_int4(ij.x, ij.y, 0, 0);
        rp = make_float4(R * R, ntf(vdep + u), ntf(vthr + u), 0.f);
    }
}

template <bool USE_WS>
__global__ void __launch_bounds__(TPB, 6) uff_kernel(
    const float* __restrict__ coords, const float4* __restrict__ cw,
    const int* __restrict__ bidx, const float* __restrict__ br0, const float* __restrict__ bk,
    const int* __restrict__ aidx, const float* __restrict__ ak,
    const float* __restrict__ ac0, const float* __restrict__ ac1, const float* __restrict__ ac2,
    const int* __restrict__ tidx, const float* __restrict__ tk,
    const int* __restrict__ tord, const float* __restrict__ tcos,
    const int* __restrict__ iidx, const float* __restrict__ ik,
    const float* __restrict__ ic0, const float* __restrict__ ic1, const float* __restrict__ ic2,
    const int* __restrict__ nidx, const float* __restrict__ vmin,
    const float* __restrict__ vdep, const float* __restrict__ vthr,
    float* __restrict__ out, SegInfo s)
{
    // Per-wave staging slice (8 KB/block). Barrier-free: only the owning wave
    // touches its slice (same-wave ds ordering via lgkmcnt).
    __shared__ int4   sI[NWAVE][64];
    __shared__ float4 sP[NWAVE][64];

    const int tid = threadIdx.x;
    const int lane = tid & 63;
    const int w = tid >> 6;
    const int b = lane & 7;       // this lane's batch
    const int gw = lane >> 3;     // group within wave, 0..7
    const int N = s.N;
    float acc = 0.f;

    int4*   mI = sI[w];
    float4* mP = sP[w];

    const int stride = gridDim.x * NWAVE;
    int c = blockIdx.x * NWAVE + w;

    // Software pipeline: prefetch chunk c's params into registers.
    int4 ri; float4 rp;
    if (c < s.cl)
        stage(c, s, lane, bidx, br0, bk, aidx, ak, ac0, ac1, ac2,
              tidx, tk, tord, tcos, iidx, ik, ic0, ic1, ic2,
              nidx, vmin, vdep, vthr, ri, rp);

    while (c < s.cl) {
        mI[lane] = ri;
        mP[lane] = rp;

        int kind, base;
        if (c < s.cb)      { kind = 0; base = c * 64; }
        else if (c < s.ca) { kind = 1; base = (c - s.cb) * 64; }
        else if (c < s.ct) { kind = 2; base = (c - s.ca) * 64; }
        else if (c < s.ci) { kind = 3; base = (c - s.ct) * 64; }
        else               { kind = 4; base = (c - s.ci) * 64; }

        // Issue next chunk's staging loads (independent of this chunk's compute).
        const int cn = c + stride;
        if (cn < s.cl)
            stage(cn, s, lane, bidx, br0, bk, aidx, ak, ac0, ac1, ac2,
                  tidx, tk, tord, tcos, iidx, ik, ic0, ic1, ic2,
                  nidx, vmin, vdep, vthr, ri, rp);

        // ------- process: 8 lanes per term, one batch per lane; phase-separated -------
        // loads (all issued) -> compute (all consumed) so 6-8 gathers stay in flight.
        if (kind == 4) {
            // vdW LJ: 4 terms per pass = 8 gathers in flight
#pragma unroll
            for (int jj = 0; jj < 2; jj++) {
                int4 q[4]; float4 p[4], A[4], Bv[4];
#pragma unroll
                for (int j = 0; j < 4; j++) {
                    const int slot = (jj * 4 + j) * 8 + gw;
                    q[j] = mI[slot]; p[j] = mP[slot];
                }
#pragma unroll
                for (int j = 0; j < 4; j++) {
                    A[j]  = loadC<USE_WS>(cw, coords, N, q[j].x, b);
                    Bv[j] = loadC<USE_WS>(cw, coords, N, q[j].y, b);
                }
#pragma unroll
                for (int j = 0; j < 4; j++) {
                    float dx = A[j].x - Bv[j].x, dy = A[j].y - Bv[j].y, dz = A[j].z - Bv[j].z;
                    float d2 = dx * dx + dy * dy + dz * dz;
                    float x2 = p[j].x / fmaxf(d2, 1e-12f);
                    float x6 = x2 * x2 * x2;
                    float e = p[j].y * (x6 * x6 - 2.f * x6);
                    if (base + (jj * 4 + j) * 8 + gw < s.NC && d2 <= p[j].z) acc += e;
                }
            }
        } else if (kind == 0) {
            // bond stretch: 4 terms per pass = 8 gathers in flight
#pragma unroll
            for (int jj = 0; jj < 2; jj++) {
                int4 q[4]; float4 p[4], A[4], Bv[4];
#pragma unroll
                for (int j = 0; j < 4; j++) {
                    const int slot = (jj * 4 + j) * 8 + gw;
                    q[j] = mI[slot]; p[j] = mP[slot];
                }
#pragma unroll
                for (int j = 0; j < 4; j++) {
                    A[j]  = loadC<USE_WS>(cw, coords, N, q[j].x, b);
                    Bv[j] = loadC<USE_WS>(cw, coords, N, q[j].y, b);
                }
#pragma unroll
                for (int j = 0; j < 4; j++) {
                    float dx = A[j].x - Bv[j].x, dy = A[j].y - Bv[j].y, dz = A[j].z - Bv[j].z;
                    float dd = sqrtf(dx * dx + dy * dy + dz * dz) - p[j].x;
                    if (base + (jj * 4 + j) * 8 + gw < s.NB) acc += 0.5f * p[j].y * dd * dd;
                }
            }
        } else if (kind == 1) {
            // angle bend: 2 terms per pass = 6 gathers in flight
#pragma unroll
            for (int jj = 0; jj < 4; jj++) {
                int4 q[2]; float4 p[2], P[2], Q[2], R[2];
#pragma unroll
                for (int j = 0; j < 2; j++) {
                    const int slot = (jj * 2 + j) * 8 + gw;
                    q[j] = mI[slot]; p[j] = mP[slot];
                }
#pragma unroll
                for (int j = 0; j < 2; j++) {
                    P[j] = loadC<USE_WS>(cw, coords, N, q[j].x, b);
                    Q[j] = loadC<USE_WS>(cw, coords, N, q[j].y, b);
                    R[j] = loadC<USE_WS>(cw, coords, N, q[j].z, b);
                }
#pragma unroll
                for (int j = 0; j < 2; j++) {
                    float ax = P[j].x - Q[j].x, ay = P[j].y - Q[j].y, az = P[j].z - Q[j].z;
                    float bx = R[j].x - Q[j].x, by = R[j].y - Q[j].y, bz = R[j].z - Q[j].z;
                    float dot = ax * bx + ay * by + az * bz;
                    float nn = (ax * ax + ay * ay + az * az) * (bx * bx + by * by + bz * bz);
                    float ct = clamp1(dot * rsqrtf(fmaxf(nn, 1e-24f)));
                    float cs = ct * ct;
                    float sb = fmaxf(1.f - cs, 1e-12f);
                    if (base + (jj * 2 + j) * 8 + gw < s.NA)
                        acc += p[j].x * (p[j].y + p[j].z * ct + p[j].w * (cs - sb));
                }
            }
        } else if (kind == 2) {
            // torsion: 2 terms per pass = 8 gathers in flight
#pragma unroll
            for (int jj = 0; jj < 4; jj++) {
                int4 q[2]; float4 p[2], P1[2], P2[2], P3[2], P4[2];
#pragma unroll
                for (int j = 0; j < 2; j++) {
                    const int slot = (jj * 2 + j) * 8 + gw;
                    q[j] = mI[slot]; p[j] = mP[slot];
                }
#pragma unroll
                for (int j = 0; j < 2; j++) {
                    P1[j] = loadC<USE_WS>(cw, coords, N, q[j].x, b);
                    P2[j] = loadC<USE_WS>(cw, coords, N, q[j].y, b);
                    P3[j] = loadC<USE_WS>(cw, coords, N, q[j].z, b);
                    P4[j] = loadC<USE_WS>(cw, coords, N, q[j].w, b);
                }
#pragma unroll
                for (int j = 0; j < 2; j++) {
                    const int ord = __float_as_int(p[j].z);
                    float b1x = P2[j].x - P1[j].x, b1y = P2[j].y - P1[j].y, b1z = P2[j].z - P1[j].z;
                    float b2x = P3[j].x - P2[j].x, b2y = P3[j].y - P2[j].y, b2z = P3[j].z - P2[j].z;
                    float b3x = P4[j].x - P3[j].x, b3y = P4[j].y - P3[j].y, b3z = P4[j].z - P3[j].z;
                    float n1x = b1y * b2z - b1z * b2y;
                    float n1y = b1z * b2x - b1x * b2z;
                    float n1z = b1x * b2y - b1y * b2x;
                    float n2x = b2y * b3z - b2z * b3y;
                    float n2y = b2z * b3x - b2x * b3z;
                    float n2z = b2x * b3y - b2y * b3x;
                    float dot = n1x * n2x + n1y * n2y + n1z * n2z;
                    float nn = (n1x * n1x + n1y * n1y + n1z * n1z) *
                               (n2x * n2x + n2y * n2y + n2z * n2z);
                    float x = clamp1(dot * rsqrtf(fmaxf(nn, 1e-24f)));
                    // cos(n*acos(x)) = T_n(x), n in [1,6]
                    float Tp = 1.f, Tc = x, res = x;
#pragma unroll
                    for (int kk = 2; kk <= 6; kk++) {
                        float Tn = 2.f * x * Tc - Tp;
                        Tp = Tc; Tc = Tn;
                        if (ord == kk) res = Tn;
                    }
                    if (base + (jj * 2 + j) * 8 + gw < s.NT) acc += 0.5f * p[j].x * (1.f - p[j].y * res);
                }
            }
        } else {
            // inversion (Wilson): 2 terms per pass = 8 gathers in flight
#pragma unroll
            for (int jj = 0; jj < 4; jj++) {
                int4 q[2]; float4 p[2], CA[2], PI[2], PK[2], PL[2];
#pragma unroll
                for (int j = 0; j < 2; j++) {
                    const int slot = (jj * 2 + j) * 8 + gw;
                    q[j] = mI[slot]; p[j] = mP[slot];
                }
#pragma unroll
                for (int j = 0; j < 2; j++) {
                    CA[j] = loadC<USE_WS>(cw, coords, N, q[j].y, b);
                    PI[j] = loadC<USE_WS>(cw, coords, N, q[j].x, b);
                    PK[j] = loadC<USE_WS>(cw, coords, N, q[j].z, b);
                    PL[j] = loadC<USE_WS>(cw, coords, N, q[j].w, b);
                }
#pragma unroll
                for (int j = 0; j < 2; j++) {
                    float jix = PI[j].x - CA[j].x, jiy = PI[j].y - CA[j].y, jiz = PI[j].z - CA[j].z;
                    float jkx = PK[j].x - CA[j].x, jky = PK[j].y - CA[j].y, jkz = PK[j].z - CA[j].z;
                    float lx  = PL[j].x - CA[j].x, ly  = PL[j].y - CA[j].y, lz  = PL[j].z - CA[j].z;
                    float nx = jiy * jkz - jiz * jky;
                    float ny = jiz * jkx - jix * jkz;
                    float nz = jix * jky - jiy * jkx;
                    float dot = nx * lx + ny * ly + nz * lz;
                    float nn = (nx * nx + ny * ny + nz * nz) * (lx * lx + ly * ly + lz * lz);
                    float cosY = clamp1(dot * rsqrtf(fmaxf(nn, 1e-24f)));
                    float sinY = sqrtf(fmaxf(1.f - cosY * cosY, 0.f));
                    if (base + (jj * 2 + j) * 8 + gw < s.NI)
                        acc += p[j].x * (p[j].y + p[j].z * sinY + p[j].w * (2.f * sinY * sinY - 1.f));
                }
            }
        }

        c = cn;
    }

    // ---------------- reduction: lanes with same (lane&7) hold same batch ----------------
    float v = acc;
    v += __shfl_down(v, 8, 64);
    v += __shfl_down(v, 16, 64);
    v += __shfl_down(v, 32, 64);
    // lanes 0..7 of each wave now hold batch 0..7 sums

    __shared__ float red[NWAVE][8];
    if (lane < 8) red[w][lane] = v;
    __syncthreads();
    if (tid < 8) {
        float ssum = 0.f;
#pragma unroll
        for (int i = 0; i < NWAVE; i++) ssum += red[i][tid];
        atomicAdd(&out[tid], ssum);
    }
}

static inline int cdiv(int a, int b) { return (a + b - 1) / b; }

extern "C" void kernel_launch(void* const* d_in, const int* in_sizes, int n_in,
                              void* d_out, int out_size, void* d_ws, size_t ws_size,
                              hipStream_t stream) {
    const int B = out_size;  // expected 8 (kernel hard-codes 8 batches)
    const int NB = in_sizes[2], NA = in_sizes[5], NT = in_sizes[10],
              NI = in_sizes[14], NC = in_sizes[19];
    const int N = in_sizes[0] / (3 * B);

    const float* coords = (const float*)d_in[0];
    const int*   bidx = (const int*)d_in[1];
    const float* br0  = (const float*)d_in[2];
    const float* bk   = (const float*)d_in[3];
    const int*   aidx = (const int*)d_in[4];
    const float* ak   = (const float*)d_in[5];
    const float* ac0  = (const float*)d_in[6];
    const float* ac1  = (const float*)d_in[7];
    const float* ac2  = (const float*)d_in[8];
    const int*   tidx = (const int*)d_in[9];
    const float* tk   = (const float*)d_in[10];
    const int*   tord = (const int*)d_in[11];
    const float* tcos = (const float*)d_in[12];
    const int*   iidx = (const int*)d_in[13];
    const float* ik   = (const float*)d_in[14];
    const float* ic0  = (const float*)d_in[15];
    const float* ic1  = (const float*)d_in[16];
    const float* ic2  = (const float*)d_in[17];
    const int*   nidx = (const int*)d_in[18];
    const float* vmin = (const float*)d_in[19];
    const float* vdep = (const float*)d_in[20];
    const float* vthr = (const float*)d_in[21];

    const size_t cw_bytes = (size_t)N * 8 * sizeof(float4);
    const bool use_ws = ws_size >= cw_bytes;
    float4* cw = (float4*)d_ws;

    if (use_ws) {
        transpose_coords<<<cdiv(N, TPB), TPB, 0, stream>>>(coords, cw, (float*)d_out, N);
    } else {
        hipMemsetAsync(d_out, 0, (size_t)out_size * sizeof(float), stream);
    }

    SegInfo s;
    s.NB = NB; s.NA = NA; s.NT = NT; s.NI = NI; s.NC = NC; s.N = N;
    s.cb = cdiv(NB, 64);
    s.ca = s.cb + cdiv(NA, 64);
    s.ct = s.ca + cdiv(NT, 64);
    s.ci = s.ct + cdiv(NI, 64);
    s.cl = s.ci + cdiv(NC, 64);

    if (use_ws) {
        uff_kernel<true><<<GRID_MAIN, TPB, 0, stream>>>(
            coords, cw, bidx, br0, bk, aidx, ak, ac0, ac1, ac2,
            tidx, tk, tord, tcos, iidx, ik, ic0, ic1, ic2,
            nidx, vmin, vdep, vthr, (float*)d_out, s);
    } else {
        uff_kernel<false><<<GRID_MAIN, TPB, 0, stream>>>(
            coords, cw, bidx, br0, bk, aidx, ak, ac0, ac1, ac2,
            tidx, tk, tord, tcos, iidx, ik, ic0, ic1, ic2,
            nidx, vmin, vdep, vthr, (float*)d_out, s);
    }
}